// Round 1
// baseline (547.539 us; speedup 1.0000x reference)
//
#include <hip/hip_runtime.h>

// SelfAttention: y = causal_mha(x @ W_qkv^T + b_qkv)
// B=4, T=2048, C=1024, H=16, hd=64.  All I/O fp32; compute in bf16 MFMA.
//
// Pipeline:
//   1) cvt_bf16: x (8.4M f32) -> xb bf16 ; W (3.1M f32) -> Wb bf16
//   2) qkv_gemm: [8192,3072] = xb[8192,1024] @ Wb[3072,1024]^T + bias
//      epilogue scatters to q[bh][t][64] (pre-scaled by 0.125), k[bh][t][64],
//      vT[bh][64][t]  (all bf16, in d_ws)
//   3) attn: flash attention, 4 waves/block, 16 q-rows/wave, KVBLK=32,
//      16x16x32 bf16 MFMA, online softmax, P transposed via per-wave LDS.
//
// ws layout (bytes): xb @0 (16MiB), Wb @16777216 (6MiB), q @23068672,
//                    k @39845888, vT @56623104, end 73400320.

typedef unsigned short u16;
typedef short bf16x8 __attribute__((ext_vector_type(8)));
typedef float f32x4 __attribute__((ext_vector_type(4)));

__device__ __forceinline__ u16 f2b(float f) {
  union { float f; unsigned u; } x; x.f = f;
  unsigned r = x.u + 0x7FFFu + ((x.u >> 16) & 1u);  // RNE
  return (u16)(r >> 16);
}

__device__ __forceinline__ void gload16(const void* g, void* l) {
  __builtin_amdgcn_global_load_lds(
      (const __attribute__((address_space(1))) unsigned*)g,
      (__attribute__((address_space(3))) unsigned*)l, 16, 0, 0);
}

// ---------------- fp32 -> bf16 convert ----------------
__global__ void cvt_bf16(const float* __restrict__ src, u16* __restrict__ dst, int n4) {
  int i = blockIdx.x * blockDim.x + threadIdx.x;
  const int stride = gridDim.x * blockDim.x;
  for (; i < n4; i += stride) {
    float4 v = ((const float4*)src)[i];
    ushort4 o;
    o.x = f2b(v.x); o.y = f2b(v.y); o.z = f2b(v.z); o.w = f2b(v.w);
    ((ushort4*)dst)[i] = o;
  }
}

// ---------------- QKV GEMM (m97 structure) ----------------
// C[8192,3072] = Xb @ Wb^T + bias.  128x128 tile, BK=32, 256 thr, 4 waves
// each owning a 64x64 quadrant (4x4 frags of 16x16x32).
__global__ __launch_bounds__(256) void qkv_gemm(
    const u16* __restrict__ Xb, const u16* __restrict__ Wb,
    const float* __restrict__ bias,
    u16* __restrict__ qw, u16* __restrict__ kw, u16* __restrict__ vT) {
  __shared__ u16 As[128 * 32];   // [row][k] row-major, 64B rows
  __shared__ u16 Bs[128 * 32];
  const int tid  = threadIdx.x;
  const int lane = tid & 63;
  const int wave = tid >> 6;
  const int ln = lane & 15, hi = lane >> 4;
  const int wr = wave >> 1, wc = wave & 1;
  const int m0 = blockIdx.y * 128;
  const int n0 = blockIdx.x * 128;

  const int srow = tid >> 2;         // staging row 0..63 (+64 second issue)
  const int scol = (tid & 3) * 8;    // staging k-offset (elements)

  f32x4 zero = {0.f, 0.f, 0.f, 0.f};
  f32x4 acc[4][4];
#pragma unroll
  for (int i = 0; i < 4; ++i)
#pragma unroll
    for (int j = 0; j < 4; ++j) acc[i][j] = zero;

  for (int k0 = 0; k0 < 1024; k0 += 32) {
    gload16(Xb + (size_t)(m0 + srow) * 1024 + k0 + scol,      (char*)As + tid * 16);
    gload16(Xb + (size_t)(m0 + 64 + srow) * 1024 + k0 + scol, (char*)As + 4096 + tid * 16);
    gload16(Wb + (size_t)(n0 + srow) * 1024 + k0 + scol,      (char*)Bs + tid * 16);
    gload16(Wb + (size_t)(n0 + 64 + srow) * 1024 + k0 + scol, (char*)Bs + 4096 + tid * 16);
    __syncthreads();   // drains vmcnt -> LDS tiles ready

    bf16x8 af[4], bfv[4];
#pragma unroll
    for (int i = 0; i < 4; ++i)
      af[i] = *(const bf16x8*)&As[(wr * 64 + i * 16 + ln) * 32 + hi * 8];
#pragma unroll
    for (int j = 0; j < 4; ++j)
      bfv[j] = *(const bf16x8*)&Bs[(wc * 64 + j * 16 + ln) * 32 + hi * 8];
#pragma unroll
    for (int i = 0; i < 4; ++i)
#pragma unroll
      for (int j = 0; j < 4; ++j)
        acc[i][j] = __builtin_amdgcn_mfma_f32_16x16x32_bf16(af[i], bfv[j], acc[i][j], 0, 0, 0);
    __syncthreads();   // all reads done before next stage overwrites
  }

  // Epilogue: bias + scatter to q/k/vT.  col -> which tensor (uniform per frag).
#pragma unroll
  for (int j = 0; j < 4; ++j) {
    const int col = n0 + wc * 64 + j * 16 + ln;
    const int which = col >> 10;          // 0=q 1=k 2=v
    const int rem = col & 1023;
    const int h = rem >> 6, d = rem & 63;
    const float bv = bias[col];
#pragma unroll
    for (int i = 0; i < 4; ++i) {
      const int rowb = m0 + wr * 64 + i * 16 + hi * 4;
#pragma unroll
      for (int r = 0; r < 4; ++r) {
        const int row = rowb + r;                 // global (b*T + t)
        const int bb = row >> 11;
        const int t = row & 2047;
        const size_t bh = (size_t)(bb * 16 + h);
        const float val = acc[i][j][r] + bv;
        if (which == 0)       qw[(bh * 2048 + t) * 64 + d] = f2b(val * 0.125f);
        else if (which == 1)  kw[(bh * 2048 + t) * 64 + d] = f2b(val);
        else                  vT[(bh * 64 + d) * 2048 + t] = f2b(val);
      }
    }
  }
}

// ---------------- Flash attention ----------------
// grid (T/64, B*H).  4 waves; wave w owns q-rows [bx*64+w*16, +16).
// KVBLK=32.  S = Q.K^T via 2x (16x16x32) per 16-col half; online softmax;
// P -> bf16 -> per-wave LDS transpose -> PV via 4x (16x16x32).
__global__ __launch_bounds__(256) void attn(
    const u16* __restrict__ qw, const u16* __restrict__ kw,
    const u16* __restrict__ vT, float* __restrict__ y) {
  __shared__ u16 P[4][16 * 32];   // 1KB per wave
  const int tid  = threadIdx.x;
  const int lane = tid & 63;
  const int wave = tid >> 6;
  const int ln = lane & 15, hi = lane >> 4;
  const int bh = blockIdx.y;
  const int bb = bh >> 4, h = bh & 15;
  const int q0 = blockIdx.x * 64 + wave * 16;

  const u16* qb = qw + (size_t)bh * 2048 * 64;
  const u16* kb = kw + (size_t)bh * 2048 * 64;
  const u16* vb = vT + (size_t)bh * 64 * 2048;

  // Q fragments (A operand), hoisted: row = q0+ln, k = hi*8 (+32 second half)
  const bf16x8 qf0 = *(const bf16x8*)&qb[(q0 + ln) * 64 + hi * 8];
  const bf16x8 qf1 = *(const bf16x8*)&qb[(q0 + ln) * 64 + 32 + hi * 8];

  f32x4 zero = {0.f, 0.f, 0.f, 0.f};
  float mrow[4], lrow[4];
  f32x4 acc[4];
#pragma unroll
  for (int r = 0; r < 4; ++r) { mrow[r] = -1e30f; lrow[r] = 0.f; }
#pragma unroll
  for (int db = 0; db < 4; ++db) acc[db] = zero;

  const int jt_end = blockIdx.x * 2 + 1;   // uniform across block (for barriers)
  u16* myP = &P[wave][0];

  for (int jt = 0; jt <= jt_end; ++jt) {
    const int kvb = jt * 32;
    f32x4 s[2];
#pragma unroll
    for (int c = 0; c < 2; ++c) {
      const int krow = kvb + c * 16 + ln;
      const bf16x8 kf0 = *(const bf16x8*)&kb[krow * 64 + hi * 8];
      const bf16x8 kf1 = *(const bf16x8*)&kb[krow * 64 + 32 + hi * 8];
      f32x4 z = __builtin_amdgcn_mfma_f32_16x16x32_bf16(qf0, kf0, zero, 0, 0, 0);
      s[c] = __builtin_amdgcn_mfma_f32_16x16x32_bf16(qf1, kf1, z, 0, 0, 0);
      // causal mask: C/D layout row = hi*4+r, col = ln
#pragma unroll
      for (int r = 0; r < 4; ++r)
        if (krow > q0 + hi * 4 + r) s[c][r] = -1e30f;
    }

    float e0a[4], e1a[4];
#pragma unroll
    for (int r = 0; r < 4; ++r) {
      float mc = fmaxf(s[0][r], s[1][r]);
#pragma unroll
      for (int off = 1; off < 16; off <<= 1) mc = fmaxf(mc, __shfl_xor(mc, off));
      const float mn = fmaxf(mrow[r], mc);
      const float a  = __expf(mrow[r] - mn);
      mrow[r] = mn;
      const float e0 = __expf(s[0][r] - mn);
      const float e1 = __expf(s[1][r] - mn);
      float ps = e0 + e1;
#pragma unroll
      for (int off = 1; off < 16; off <<= 1) ps += __shfl_xor(ps, off);
      lrow[r] = lrow[r] * a + ps;
#pragma unroll
      for (int db = 0; db < 4; ++db) acc[db][r] *= a;
      e0a[r] = e0; e1a[r] = e1;
    }

    __syncthreads();   // previous iteration's P reads done (belt & braces)
#pragma unroll
    for (int r = 0; r < 4; ++r) {
      myP[(hi * 4 + r) * 32 + ln]      = f2b(e0a[r]);
      myP[(hi * 4 + r) * 32 + 16 + ln] = f2b(e1a[r]);
    }
    __syncthreads();   // P visible

    const bf16x8 pf = *(const bf16x8*)&myP[ln * 32 + hi * 8];
#pragma unroll
    for (int db = 0; db < 4; ++db) {
      const bf16x8 vf = *(const bf16x8*)&vb[(db * 16 + ln) * 2048 + kvb + hi * 8];
      acc[db] = __builtin_amdgcn_mfma_f32_16x16x32_bf16(pf, vf, acc[db], 0, 0, 0);
    }
  }

  // y[b][t][h*64 + d]
  float* yb = y + (size_t)bb * 2048 * 1024 + (size_t)h * 64;
#pragma unroll
  for (int r = 0; r < 4; ++r) {
    const int t = q0 + hi * 4 + r;
    const float inv = 1.0f / lrow[r];
#pragma unroll
    for (int db = 0; db < 4; ++db)
      yb[(size_t)t * 1024 + db * 16 + ln] = acc[db][r] * inv;
  }
}

extern "C" void kernel_launch(void* const* d_in, const int* in_sizes, int n_in,
                              void* d_out, int out_size, void* d_ws, size_t ws_size,
                              hipStream_t stream) {
  const float* x    = (const float*)d_in[0];   // [4,2048,1024]
  const float* W    = (const float*)d_in[1];   // [3072,1024]
  const float* bias = (const float*)d_in[2];   // [3072]
  float* y = (float*)d_out;

  char* ws = (char*)d_ws;
  u16* xb = (u16*)(ws);
  u16* Wb = (u16*)(ws + 16777216);
  u16* qw = (u16*)(ws + 23068672);
  u16* kw = (u16*)(ws + 39845888);
  u16* vT = (u16*)(ws + 56623104);

  cvt_bf16<<<2048, 256, 0, stream>>>(x, xb, 8388608 / 4);
  cvt_bf16<<<1024, 256, 0, stream>>>(W, Wb, 3145728 / 4);
  qkv_gemm<<<dim3(24, 64), 256, 0, stream>>>(xb, Wb, bias, qw, kw, vT);
  attn<<<dim3(32, 64), 256, 0, stream>>>(qw, kw, vT, y);
}

// Round 2
// 328.697 us; speedup vs baseline: 1.6658x; 1.6658x over previous
//
#include <hip/hip_runtime.h>

// SelfAttention: y = causal_mha(x @ W_qkv^T + b_qkv)
// B=4, T=2048, C=1024, H=16, hd=64.  All I/O fp32; compute in bf16 MFMA.
//
// Pipeline:
//   1) cvt_bf16: x -> xb bf16 ; W -> Wb bf16
//   2) qkv_gemm (m97 structure): scatters to q[bh][t][64] (pre-scaled 0.125),
//      k[bh][t][64], vT[bh][64][t]  (bf16, in d_ws)
//   3) attn v2: balanced causal flash attention.
//      - 1D grid 1024 blocks, 4 waves, 16 q-rows/wave.
//      - block handles q-tile pair {bx, 31-bx}  -> equal work per block.
//      - bh decoded from bid%8 -> all blocks of one (b,h) on one XCD (L2 reuse).
//      - no __syncthreads (P is per-wave; DS ops in-order within a wave).
//      - per-wave causal bound; row-sum l via MFMA with ones-B; defer-max THR=8.

typedef unsigned short u16;
typedef short bf16x8 __attribute__((ext_vector_type(8)));
typedef float f32x4 __attribute__((ext_vector_type(4)));

__device__ __forceinline__ u16 f2b(float f) {
  union { float f; unsigned u; } x; x.f = f;
  unsigned r = x.u + 0x7FFFu + ((x.u >> 16) & 1u);  // RNE
  return (u16)(r >> 16);
}

__device__ __forceinline__ void gload16(const void* g, void* l) {
  __builtin_amdgcn_global_load_lds(
      (const __attribute__((address_space(1))) unsigned*)g,
      (__attribute__((address_space(3))) unsigned*)l, 16, 0, 0);
}

// ---------------- fp32 -> bf16 convert ----------------
__global__ void cvt_bf16(const float* __restrict__ src, u16* __restrict__ dst, int n4) {
  int i = blockIdx.x * blockDim.x + threadIdx.x;
  const int stride = gridDim.x * blockDim.x;
  for (; i < n4; i += stride) {
    float4 v = ((const float4*)src)[i];
    ushort4 o;
    o.x = f2b(v.x); o.y = f2b(v.y); o.z = f2b(v.z); o.w = f2b(v.w);
    ((ushort4*)dst)[i] = o;
  }
}

// ---------------- QKV GEMM (m97 structure) ----------------
__global__ __launch_bounds__(256) void qkv_gemm(
    const u16* __restrict__ Xb, const u16* __restrict__ Wb,
    const float* __restrict__ bias,
    u16* __restrict__ qw, u16* __restrict__ kw, u16* __restrict__ vT) {
  __shared__ u16 As[128 * 32];
  __shared__ u16 Bs[128 * 32];
  const int tid  = threadIdx.x;
  const int lane = tid & 63;
  const int wave = tid >> 6;
  const int ln = lane & 15, hi = lane >> 4;
  const int wr = wave >> 1, wc = wave & 1;
  const int m0 = blockIdx.y * 128;
  const int n0 = blockIdx.x * 128;

  const int srow = tid >> 2;
  const int scol = (tid & 3) * 8;

  f32x4 zero = {0.f, 0.f, 0.f, 0.f};
  f32x4 acc[4][4];
#pragma unroll
  for (int i = 0; i < 4; ++i)
#pragma unroll
    for (int j = 0; j < 4; ++j) acc[i][j] = zero;

  for (int k0 = 0; k0 < 1024; k0 += 32) {
    gload16(Xb + (size_t)(m0 + srow) * 1024 + k0 + scol,      (char*)As + tid * 16);
    gload16(Xb + (size_t)(m0 + 64 + srow) * 1024 + k0 + scol, (char*)As + 4096 + tid * 16);
    gload16(Wb + (size_t)(n0 + srow) * 1024 + k0 + scol,      (char*)Bs + tid * 16);
    gload16(Wb + (size_t)(n0 + 64 + srow) * 1024 + k0 + scol, (char*)Bs + 4096 + tid * 16);
    __syncthreads();

    bf16x8 af[4], bfv[4];
#pragma unroll
    for (int i = 0; i < 4; ++i)
      af[i] = *(const bf16x8*)&As[(wr * 64 + i * 16 + ln) * 32 + hi * 8];
#pragma unroll
    for (int j = 0; j < 4; ++j)
      bfv[j] = *(const bf16x8*)&Bs[(wc * 64 + j * 16 + ln) * 32 + hi * 8];
#pragma unroll
    for (int i = 0; i < 4; ++i)
#pragma unroll
      for (int j = 0; j < 4; ++j)
        acc[i][j] = __builtin_amdgcn_mfma_f32_16x16x32_bf16(af[i], bfv[j], acc[i][j], 0, 0, 0);
    __syncthreads();
  }

#pragma unroll
  for (int j = 0; j < 4; ++j) {
    const int col = n0 + wc * 64 + j * 16 + ln;
    const int which = col >> 10;
    const int rem = col & 1023;
    const int h = rem >> 6, d = rem & 63;
    const float bv = bias[col];
#pragma unroll
    for (int i = 0; i < 4; ++i) {
      const int rowb = m0 + wr * 64 + i * 16 + hi * 4;
#pragma unroll
      for (int r = 0; r < 4; ++r) {
        const int row = rowb + r;
        const int bb = row >> 11;
        const int t = row & 2047;
        const size_t bh = (size_t)(bb * 16 + h);
        const float val = acc[i][j][r] + bv;
        if (which == 0)       qw[(bh * 2048 + t) * 64 + d] = f2b(val * 0.125f);
        else if (which == 1)  kw[(bh * 2048 + t) * 64 + d] = f2b(val);
        else                  vT[(bh * 64 + d) * 2048 + t] = f2b(val);
      }
    }
  }
}

// ---------------- Flash attention v2 (balanced, barrier-free) ----------------
__global__ __launch_bounds__(256) void attn(
    const u16* __restrict__ qw, const u16* __restrict__ kw,
    const u16* __restrict__ vT, float* __restrict__ y) {
  __shared__ u16 P[4][16 * 32];   // per-wave 1KB transpose buffer
  const int tid  = threadIdx.x;
  const int lane = tid & 63;
  const int wave = tid >> 6;
  const int ln = lane & 15, hi = lane >> 4;

  // bid = xcd + 8*(bx + 16*(bh>>3)): all 16 q-pair-blocks of one bh land on
  // one XCD (round-robin bid%8), 8 bh per XCD -> K+V (4MB) L2-resident.
  const int bid = blockIdx.x;
  const int xcd = bid & 7;
  const int r9  = bid >> 3;
  const int bx  = r9 & 15;                // q-tile pair index 0..15
  const int bh  = xcd + 8 * (r9 >> 4);    // 0..63
  const int bb  = bh >> 4, h = bh & 15;

  const u16* qb = qw + (size_t)bh * 2048 * 64;
  const u16* kb = kw + (size_t)bh * 2048 * 64;
  const u16* vb = vT + (size_t)bh * 64 * 2048;
  float* yb = y + (size_t)bb * 2048 * 1024 + (size_t)h * 64;
  u16* myP = &P[wave][0];

  bf16x8 onesf;
#pragma unroll
  for (int j = 0; j < 8; ++j) onesf[j] = (short)0x3F80;  // bf16 1.0

  f32x4 zero = {0.f, 0.f, 0.f, 0.f};

#pragma unroll 1
  for (int pi = 0; pi < 2; ++pi) {
    const int tile = pi ? (31 - bx) : bx;   // balanced pair
    const int q0 = tile * 64 + wave * 16;

    const bf16x8 qf0 = *(const bf16x8*)&qb[(q0 + ln) * 64 + hi * 8];
    const bf16x8 qf1 = *(const bf16x8*)&qb[(q0 + ln) * 64 + 32 + hi * 8];

    f32x4 acc[4];
    f32x4 lacc = zero;
    float mrow[4];
#pragma unroll
    for (int db = 0; db < 4; ++db) acc[db] = zero;
#pragma unroll
    for (int r = 0; r < 4; ++r) mrow[r] = -1e30f;

    const int jtE = (q0 + 15) >> 5;   // per-wave causal bound (inclusive)
#pragma unroll 1
    for (int jt = 0; jt <= jtE; ++jt) {
      const int kvb = jt * 32;
      f32x4 s[2];
      {
        const int krow = kvb + ln;
        const bf16x8 kf0 = *(const bf16x8*)&kb[krow * 64 + hi * 8];
        const bf16x8 kf1 = *(const bf16x8*)&kb[krow * 64 + 32 + hi * 8];
        f32x4 z = __builtin_amdgcn_mfma_f32_16x16x32_bf16(qf0, kf0, zero, 0, 0, 0);
        s[0] = __builtin_amdgcn_mfma_f32_16x16x32_bf16(qf1, kf1, z, 0, 0, 0);
      }
      if (kvb + 16 <= q0 + 15) {   // upper half-tile not fully masked
        const int krow = kvb + 16 + ln;
        const bf16x8 kf0 = *(const bf16x8*)&kb[krow * 64 + hi * 8];
        const bf16x8 kf1 = *(const bf16x8*)&kb[krow * 64 + 32 + hi * 8];
        f32x4 z = __builtin_amdgcn_mfma_f32_16x16x32_bf16(qf0, kf0, zero, 0, 0, 0);
        s[1] = __builtin_amdgcn_mfma_f32_16x16x32_bf16(qf1, kf1, z, 0, 0, 0);
      } else {
        s[1] = (f32x4){-1e30f, -1e30f, -1e30f, -1e30f};
      }

      if (kvb + 31 > q0) {   // diagonal tile: apply causal mask
#pragma unroll
        for (int c = 0; c < 2; ++c)
#pragma unroll
          for (int r = 0; r < 4; ++r)
            if (kvb + c * 16 + ln > q0 + hi * 4 + r) s[c][r] = -1e30f;
      }

      // row max (16-lane butterfly)
      float mc[4];
#pragma unroll
      for (int r = 0; r < 4; ++r) {
        float m = fmaxf(s[0][r], s[1][r]);
#pragma unroll
        for (int off = 1; off < 16; off <<= 1) m = fmaxf(m, __shfl_xor(m, off));
        mc[r] = m;
      }

      // defer-max: rescale only if max grew by > 8
      float gm = mc[0] - mrow[0];
#pragma unroll
      for (int r = 1; r < 4; ++r) gm = fmaxf(gm, mc[r] - mrow[r]);
      if (__any(gm > 8.f)) {
#pragma unroll
        for (int r = 0; r < 4; ++r) {
          const float mn = fmaxf(mrow[r], mc[r]);
          const float a  = __expf(mrow[r] - mn);
          mrow[r] = mn;
          lacc[r] *= a;
#pragma unroll
          for (int db = 0; db < 4; ++db) acc[db][r] *= a;
        }
      }

      // P = exp(S - m) -> bf16 -> per-wave LDS transpose
#pragma unroll
      for (int r = 0; r < 4; ++r) {
        myP[(hi * 4 + r) * 32 + ln]      = f2b(__expf(s[0][r] - mrow[r]));
        myP[(hi * 4 + r) * 32 + 16 + ln] = f2b(__expf(s[1][r] - mrow[r]));
      }
      // DS ops within a wave are in-order: read sees the writes above.
      const bf16x8 pf = *(const bf16x8*)&myP[ln * 32 + hi * 8];
      lacc = __builtin_amdgcn_mfma_f32_16x16x32_bf16(pf, onesf, lacc, 0, 0, 0);
#pragma unroll
      for (int db = 0; db < 4; ++db) {
        const bf16x8 vf = *(const bf16x8*)&vb[(db * 16 + ln) * 2048 + kvb + hi * 8];
        acc[db] = __builtin_amdgcn_mfma_f32_16x16x32_bf16(pf, vf, acc[db], 0, 0, 0);
      }
    }

    // y[b][t][h*64+d]
#pragma unroll
    for (int r = 0; r < 4; ++r) {
      const int t = q0 + hi * 4 + r;
      const float inv = 1.0f / lacc[r];
#pragma unroll
      for (int db = 0; db < 4; ++db)
        yb[(size_t)t * 1024 + db * 16 + ln] = acc[db][r] * inv;
    }
  }
}

extern "C" void kernel_launch(void* const* d_in, const int* in_sizes, int n_in,
                              void* d_out, int out_size, void* d_ws, size_t ws_size,
                              hipStream_t stream) {
  const float* x    = (const float*)d_in[0];   // [4,2048,1024]
  const float* W    = (const float*)d_in[1];   // [3072,1024]
  const float* bias = (const float*)d_in[2];   // [3072]
  float* y = (float*)d_out;

  char* ws = (char*)d_ws;
  u16* xb = (u16*)(ws);
  u16* Wb = (u16*)(ws + 16777216);
  u16* qw = (u16*)(ws + 23068672);
  u16* kw = (u16*)(ws + 39845888);
  u16* vT = (u16*)(ws + 56623104);

  cvt_bf16<<<2048, 256, 0, stream>>>(x, xb, 8388608 / 4);
  cvt_bf16<<<1024, 256, 0, stream>>>(W, Wb, 3145728 / 4);
  qkv_gemm<<<dim3(24, 64), 256, 0, stream>>>(xb, Wb, bias, qw, kw, vT);
  attn<<<1024, 256, 0, stream>>>(qw, kw, vT, y);
}

// Round 4
// 221.170 us; speedup vs baseline: 2.4756x; 1.4862x over previous
//
#include <hip/hip_runtime.h>

// SelfAttention: y = causal_mha(x @ W_qkv^T + b_qkv)
// B=4, T=2048, C=1024, H=16, hd=64.  All I/O fp32; compute in bf16 MFMA.
//
// Pipeline:
//   1) cvt_bf16: x -> xb bf16 ; W -> Wb bf16
//   2) qkv_gemm (m97 structure): scatters to q[bh][t][64] (pre-scaled by
//      0.125*log2e -> S in log2 domain), k[bh][t][64], vT[bh][64][t]
//   3) attn v3 (m214-style swapped-QK^T 32x32 structure):
//      - 4 waves/block, 32 q-rows/wave, KVBLK=32, no LDS, no barriers.
//      - S^T = mfma(K, Q): lane owns one q-row -> in-lane softmax,
//        1 shfl_xor(32) per reduce instead of 16-swizzle butterfly.
//      - P -> PV A-frags in-register via v_cvt_pk_bf16_f32 + permlane32_swap.
//      - defer-max (THR=8, log2 units); exp2 via __builtin_amdgcn_exp2f
//        (v_exp_f32 computes 2^x; __exp2f doesn't exist on this ROCm).
//      - K register double-buffer (prefetch jt+1); balanced tile pairs
//        {i,15-i} with wave-role swap -> exactly 65 subtiles per wave.

typedef unsigned short u16;
typedef short bf16x8 __attribute__((ext_vector_type(8)));
typedef float f32x4 __attribute__((ext_vector_type(4)));
typedef float f32x16 __attribute__((ext_vector_type(16)));

__device__ __forceinline__ float exp2f_hw(float x) {
  return __builtin_amdgcn_exp2f(x);   // v_exp_f32: 2^x
}

__device__ __forceinline__ u16 f2b(float f) {
  union { float f; unsigned u; } x; x.f = f;
  unsigned r = x.u + 0x7FFFu + ((x.u >> 16) & 1u);  // RNE
  return (u16)(r >> 16);
}

__device__ __forceinline__ unsigned cvtpk(float lo, float hi_) {
  unsigned r;
  asm("v_cvt_pk_bf16_f32 %0, %1, %2" : "=v"(r) : "v"(lo), "v"(hi_));
  return r;
}

__device__ __forceinline__ void gload16(const void* g, void* l) {
  __builtin_amdgcn_global_load_lds(
      (const __attribute__((address_space(1))) unsigned*)g,
      (__attribute__((address_space(3))) unsigned*)l, 16, 0, 0);
}

// ---------------- fp32 -> bf16 convert ----------------
__global__ void cvt_bf16(const float* __restrict__ src, u16* __restrict__ dst, int n4) {
  int i = blockIdx.x * blockDim.x + threadIdx.x;
  const int stride = gridDim.x * blockDim.x;
  for (; i < n4; i += stride) {
    float4 v = ((const float4*)src)[i];
    ushort4 o;
    o.x = f2b(v.x); o.y = f2b(v.y); o.z = f2b(v.z); o.w = f2b(v.w);
    ((ushort4*)dst)[i] = o;
  }
}

// ---------------- QKV GEMM (m97 structure) ----------------
__global__ __launch_bounds__(256) void qkv_gemm(
    const u16* __restrict__ Xb, const u16* __restrict__ Wb,
    const float* __restrict__ bias,
    u16* __restrict__ qw, u16* __restrict__ kw, u16* __restrict__ vT) {
  __shared__ u16 As[128 * 32];
  __shared__ u16 Bs[128 * 32];
  const int tid  = threadIdx.x;
  const int lane = tid & 63;
  const int wave = tid >> 6;
  const int ln = lane & 15, hi = lane >> 4;
  const int wr = wave >> 1, wc = wave & 1;
  const int m0 = blockIdx.y * 128;
  const int n0 = blockIdx.x * 128;

  const int srow = tid >> 2;
  const int scol = (tid & 3) * 8;

  f32x4 zero = {0.f, 0.f, 0.f, 0.f};
  f32x4 acc[4][4];
#pragma unroll
  for (int i = 0; i < 4; ++i)
#pragma unroll
    for (int j = 0; j < 4; ++j) acc[i][j] = zero;

  for (int k0 = 0; k0 < 1024; k0 += 32) {
    gload16(Xb + (size_t)(m0 + srow) * 1024 + k0 + scol,      (char*)As + tid * 16);
    gload16(Xb + (size_t)(m0 + 64 + srow) * 1024 + k0 + scol, (char*)As + 4096 + tid * 16);
    gload16(Wb + (size_t)(n0 + srow) * 1024 + k0 + scol,      (char*)Bs + tid * 16);
    gload16(Wb + (size_t)(n0 + 64 + srow) * 1024 + k0 + scol, (char*)Bs + 4096 + tid * 16);
    __syncthreads();

    bf16x8 af[4], bfv[4];
#pragma unroll
    for (int i = 0; i < 4; ++i)
      af[i] = *(const bf16x8*)&As[(wr * 64 + i * 16 + ln) * 32 + hi * 8];
#pragma unroll
    for (int j = 0; j < 4; ++j)
      bfv[j] = *(const bf16x8*)&Bs[(wc * 64 + j * 16 + ln) * 32 + hi * 8];
#pragma unroll
    for (int i = 0; i < 4; ++i)
#pragma unroll
      for (int j = 0; j < 4; ++j)
        acc[i][j] = __builtin_amdgcn_mfma_f32_16x16x32_bf16(af[i], bfv[j], acc[i][j], 0, 0, 0);
    __syncthreads();
  }

#pragma unroll
  for (int j = 0; j < 4; ++j) {
    const int col = n0 + wc * 64 + j * 16 + ln;
    const int which = col >> 10;
    const int rem = col & 1023;
    const int h = rem >> 6, d = rem & 63;
    const float bv = bias[col];
#pragma unroll
    for (int i = 0; i < 4; ++i) {
      const int rowb = m0 + wr * 64 + i * 16 + hi * 4;
#pragma unroll
      for (int r = 0; r < 4; ++r) {
        const int row = rowb + r;
        const int bb = row >> 11;
        const int t = row & 2047;
        const size_t bh = (size_t)(bb * 16 + h);
        const float val = acc[i][j][r] + bv;
        // Q pre-scaled by (1/8)*log2(e): S = QK^T lands in log2 domain.
        if (which == 0)       qw[(bh * 2048 + t) * 64 + d] = f2b(val * 0.1803368801111244f);
        else if (which == 1)  kw[(bh * 2048 + t) * 64 + d] = f2b(val);
        else                  vT[(bh * 64 + d) * 2048 + t] = f2b(val);
      }
    }
  }
}

// ---------------- Flash attention v3 (swapped QK^T, 32x32) ----------------
__global__ __launch_bounds__(256) void attn(
    const u16* __restrict__ qw, const u16* __restrict__ kw,
    const u16* __restrict__ vT, float* __restrict__ y) {
  const int lane = threadIdx.x & 63;
  const int wave = threadIdx.x >> 6;
  const int l31 = lane & 31;
  const int hi  = lane >> 5;

  // bid = xcd + 8*(pair + 8*bhgrp): 8 bh residues per XCD -> K+V L2-resident.
  const int bid = blockIdx.x;
  const int xcd = bid & 7;
  const int r9  = bid >> 3;
  const int pr  = r9 & 7;                 // pair index 0..7
  const int bh  = xcd + 8 * (r9 >> 3);    // 0..63
  const int bb  = bh >> 4, h = bh & 15;

  const u16* qb = qw + (size_t)bh * 2048 * 64;
  const u16* kb = kw + (size_t)bh * 2048 * 64;
  const u16* vb = vT + (size_t)bh * 64 * 2048;
  float* yb = y + (size_t)bb * 2048 * 1024 + (size_t)h * 64;

#pragma unroll 1
  for (int pi = 0; pi < 2; ++pi) {
    const int tile = pi ? (15 - pr) : pr;
    const int wsel = pi ? (3 - wave) : wave;   // wave-role swap: 65 subtiles/wave
    const int q0 = tile * 128 + wsel * 32;

    // Q as B-operand: col=l31=q, k(head dim)=s*16+hi*8+j.  Hoisted.
    bf16x8 qf[4];
    {
      const u16* qp = &qb[(size_t)(q0 + l31) * 64 + hi * 8];
#pragma unroll
      for (int s = 0; s < 4; ++s) qf[s] = *(const bf16x8*)(qp + s * 16);
    }

    f32x16 acc0, acc1;   // O[q(regs)][d(lane)], d-blocks 0..31 / 32..63
#pragma unroll
    for (int r = 0; r < 16; ++r) { acc0[r] = 0.f; acc1[r] = 0.f; }
    float mrow = -1e30f, lrow = 0.f;   // per-lane: q-row = l31 (halves mirrored)

    const int jtE = q0 >> 5;   // only jt==jtE needs the causal mask

    bf16x8 kfA[4], kfB[4];
    {
      const u16* kp = &kb[(size_t)l31 * 64 + hi * 8];
#pragma unroll
      for (int s = 0; s < 4; ++s) kfA[s] = *(const bf16x8*)(kp + s * 16);
    }

#pragma unroll 1
    for (int jt = 0; jt <= jtE; ++jt) {
      const int kvb = jt * 32;

      // V as B-operand (used after softmax): col=l31(+32)=d, k=ks*16+hi*8+j
      bf16x8 vf[4];
      {
        const u16* vp = &vb[(size_t)l31 * 2048 + kvb + hi * 8];
        vf[0] = *(const bf16x8*)(vp);
        vf[1] = *(const bf16x8*)(vp + 32 * 2048);
        vf[2] = *(const bf16x8*)(vp + 16);
        vf[3] = *(const bf16x8*)(vp + 32 * 2048 + 16);
      }

      // S^T = K_tile . Q^T : D[row=kv][col=q]; prefetch next K tile.
      f32x16 st;
#pragma unroll
      for (int r = 0; r < 16; ++r) st[r] = 0.f;
      if (!(jt & 1)) {
        if (jt < jtE) {
          const u16* kp = &kb[(size_t)(kvb + 32 + l31) * 64 + hi * 8];
#pragma unroll
          for (int s = 0; s < 4; ++s) kfB[s] = *(const bf16x8*)(kp + s * 16);
        }
#pragma unroll
        for (int s = 0; s < 4; ++s)
          st = __builtin_amdgcn_mfma_f32_32x32x16_bf16(kfA[s], qf[s], st, 0, 0, 0);
      } else {
        if (jt < jtE) {
          const u16* kp = &kb[(size_t)(kvb + 32 + l31) * 64 + hi * 8];
#pragma unroll
          for (int s = 0; s < 4; ++s) kfA[s] = *(const bf16x8*)(kp + s * 16);
        }
#pragma unroll
        for (int s = 0; s < 4; ++s)
          st = __builtin_amdgcn_mfma_f32_32x32x16_bf16(kfB[s], qf[s], st, 0, 0, 0);
      }

      // causal mask (diagonal subtile only): kv offset crow(r,hi) > q offset l31
      if (jt == jtE) {
#pragma unroll
        for (int r = 0; r < 16; ++r) {
          const int crow = (r & 3) + 8 * (r >> 2) + 4 * hi;
          if (crow > l31) st[r] = -1e30f;
        }
      }

      // row max: in-lane tree + 1 cross-half combine
      float m0 = fmaxf(fmaxf(fmaxf(st[0], st[1]), fmaxf(st[2], st[3])),
                       fmaxf(fmaxf(st[4], st[5]), fmaxf(st[6], st[7])));
      float m1 = fmaxf(fmaxf(fmaxf(st[8], st[9]), fmaxf(st[10], st[11])),
                       fmaxf(fmaxf(st[12], st[13]), fmaxf(st[14], st[15])));
      float mt = fmaxf(m0, m1);
      mt = fmaxf(mt, __shfl_xor(mt, 32));

      // defer-max: rescale only when max grew by > 8 (log2 units -> P <= 256)
      if (__any(mt > mrow + 8.f)) {
        const float mn = fmaxf(mrow, mt);
        const float al = exp2f_hw(mrow - mn);
        mrow = mn;
        lrow *= al;
#pragma unroll
        for (int r = 0; r < 16; ++r) {
          const float ar = __shfl(al, (r & 3) + 8 * (r >> 2) + 4 * hi);
          acc0[r] *= ar; acc1[r] *= ar;
        }
      }

      // P = exp2(S - m); row sum
#pragma unroll
      for (int r = 0; r < 16; ++r) st[r] = exp2f_hw(st[r] - mrow);
      float p0 = ((st[0] + st[1]) + (st[2] + st[3])) + ((st[4] + st[5]) + (st[6] + st[7]));
      float p1 = ((st[8] + st[9]) + (st[10] + st[11])) + ((st[12] + st[13]) + (st[14] + st[15]));
      float ps = p0 + p1;
      ps += __shfl_xor(ps, 32);
      lrow += ps;

      // pack P into PV A-frags: 8 cvt_pk + 4 permlane32_swap
      bf16x8 pa0, pa1;
      {
        unsigned x0 = cvtpk(st[0], st[1]),  y0 = cvtpk(st[4], st[5]);
        unsigned x1 = cvtpk(st[2], st[3]),  y1 = cvtpk(st[6], st[7]);
        auto s0 = __builtin_amdgcn_permlane32_swap(x0, y0, false, false);
        auto s1 = __builtin_amdgcn_permlane32_swap(x1, y1, false, false);
        union { unsigned w[4]; bf16x8 v; } u;
        u.w[0] = s0[0]; u.w[1] = s1[0]; u.w[2] = s0[1]; u.w[3] = s1[1];
        pa0 = u.v;
      }
      {
        unsigned x0 = cvtpk(st[8], st[9]),   y0 = cvtpk(st[12], st[13]);
        unsigned x1 = cvtpk(st[10], st[11]), y1 = cvtpk(st[14], st[15]);
        auto s0 = __builtin_amdgcn_permlane32_swap(x0, y0, false, false);
        auto s1 = __builtin_amdgcn_permlane32_swap(x1, y1, false, false);
        union { unsigned w[4]; bf16x8 v; } u;
        u.w[0] = s0[0]; u.w[1] = s1[0]; u.w[2] = s0[1]; u.w[3] = s1[1];
        pa1 = u.v;
      }

      acc0 = __builtin_amdgcn_mfma_f32_32x32x16_bf16(pa0, vf[0], acc0, 0, 0, 0);
      acc1 = __builtin_amdgcn_mfma_f32_32x32x16_bf16(pa0, vf[1], acc1, 0, 0, 0);
      acc0 = __builtin_amdgcn_mfma_f32_32x32x16_bf16(pa1, vf[2], acc0, 0, 0, 0);
      acc1 = __builtin_amdgcn_mfma_f32_32x32x16_bf16(pa1, vf[3], acc1, 0, 0, 0);
    }

    // y[b][t][h*64+d]; t = q0 + crow(r,hi), d = dblk*32 + l31
    const float inv = 1.0f / lrow;
#pragma unroll
    for (int r = 0; r < 16; ++r) {
      const int crow = (r & 3) + 8 * (r >> 2) + 4 * hi;
      const float ir = __shfl(inv, crow);
      const size_t t = q0 + crow;
      yb[t * 1024 + l31]      = acc0[r] * ir;
      yb[t * 1024 + 32 + l31] = acc1[r] * ir;
    }
  }
}

extern "C" void kernel_launch(void* const* d_in, const int* in_sizes, int n_in,
                              void* d_out, int out_size, void* d_ws, size_t ws_size,
                              hipStream_t stream) {
  const float* x    = (const float*)d_in[0];   // [4,2048,1024]
  const float* W    = (const float*)d_in[1];   // [3072,1024]
  const float* bias = (const float*)d_in[2];   // [3072]
  float* y = (float*)d_out;

  char* ws = (char*)d_ws;
  u16* xb = (u16*)(ws);
  u16* Wb = (u16*)(ws + 16777216);
  u16* qw = (u16*)(ws + 23068672);
  u16* kw = (u16*)(ws + 39845888);
  u16* vT = (u16*)(ws + 56623104);

  cvt_bf16<<<2048, 256, 0, stream>>>(x, xb, 8388608 / 4);
  cvt_bf16<<<1024, 256, 0, stream>>>(W, Wb, 3145728 / 4);
  qkv_gemm<<<dim3(24, 64), 256, 0, stream>>>(xb, Wb, bias, qw, kw, vT);
  attn<<<512, 256, 0, stream>>>(qw, kw, vT, y);
}